// Round 3
// baseline (766.551 us; speedup 1.0000x reference)
//
#include <hip/hip_runtime.h>

// SSIM loss, fused separable. B*C=48 images of 512x512 fp32, 11x11 Gaussian
// window, separable via row-sums (w1[i] = sum_j window[i][j]; sum(w1)==1).
//
// Round-3: round-2's structure minus the scratch spill. Round 2 regressed
// 179->664 us because reinterpret_cast<float*> of local float4 arrays
// defeated SROA -> pv/tv/P/Q demoted to scratch (WRITE_SIZE 295 MB).
// Fix: extract float4 components BY NAME (constant indices only).
//  - h-pass: (1 row x 4 cols)/thread, global float4 loads (L1/L2-cached),
//    per-field-sequential conv to cap live registers, b128 hb writes
//    (bank pattern 4g -> proven conflict-free in round 2).
//  - v-pass: (1 col x 8 rows)/thread, 18 ds_read_b32 per 8 outputs per
//    field (bank = lane&31 -> 2-way aliasing = free on CDNA4).
//  - finalize folded in via last-block-done counter.

#define WSZ   11
#define RAD   5
#define TILE  32
#define IN    42          // TILE + 2*RAD
#define BLOCK 256
#define NWAVE (BLOCK/64)

__global__ __launch_bounds__(BLOCK, 4) void ssim_fused_kernel(
    const float* __restrict__ pred,
    const float* __restrict__ target,
    const float* __restrict__ window,
    double* __restrict__ acc,
    unsigned* __restrict__ counter,
    float* __restrict__ out,
    int H, int W, double invN)
{
    __shared__ float hb[5][IN][TILE];   // h-blurred: mu1s, mu2s, pp, pt, tt
    __shared__ float w1s[WSZ];
    __shared__ float wavesum[NWAVE];

    const int t = threadIdx.x;

    // Recover separable 1D window (row sums of the 2D window).
    if (t < WSZ) {
        float s = 0.f;
        #pragma unroll
        for (int j = 0; j < WSZ; ++j) s += window[t * WSZ + j];
        w1s[t] = s;
    }

    const int tiles_x = W / TILE;
    const int tiles_per_img = tiles_x * (H / TILE);
    const int img = blockIdx.x / tiles_per_img;
    const int rem = blockIdx.x % tiles_per_img;
    const int tyi = rem / tiles_x;
    const int txi = rem % tiles_x;
    const int row0 = tyi * TILE - RAD;
    const int col0 = txi * TILE - RAD;

    const float* __restrict__ p = pred   + (size_t)img * H * W;
    const float* __restrict__ q = target + (size_t)img * H * W;

    __syncthreads();
    float w[WSZ];
    #pragma unroll
    for (int k = 0; k < WSZ; ++k) w[k] = w1s[k];

    // Interior iff every float4 the vector path touches is in-bounds:
    // cols [txi*32-8, txi*32+39], rows [tyi*32-5, tyi*32+36].
    const bool interior = (txi > 0) && (txi * TILE + 40 <= W) &&
                          (tyi > 0) && (tyi * TILE + 37 <= H);

    // Horizontal conv of src[0..13] -> 4 outputs, written as one b128.
    auto hconv_store = [&](const float src[14], int f, int r, int g) {
        float4 o;
        float s0 = 0.f, s1 = 0.f, s2 = 0.f, s3 = 0.f;
        #pragma unroll
        for (int k = 0; k < WSZ; ++k) {
            const float wk = w[k];
            s0 += wk * src[k];
            s1 += wk * src[k + 1];
            s2 += wk * src[k + 2];
            s3 += wk * src[k + 3];
        }
        o.x = s0; o.y = s1; o.z = s2; o.w = s3;
        *reinterpret_cast<float4*>(&hb[f][r][4 * g]) = o;
    };

    // ---- Horizontal pass: unit u = (row r, col-group g of 4) ; 42*8=336 ----
    for (int u = t; u < IN * 8; u += BLOCK) {
        const int r = u >> 3, g = u & 7;
        const int gr = row0 + r;

        float pv[14], tv[14];   // abs cols col0+4g .. col0+4g+13
        if (interior) {
            const float4* __restrict__ prow =
                reinterpret_cast<const float4*>(p + (size_t)gr * W);
            const float4* __restrict__ qrow =
                reinterpret_cast<const float4*>(q + (size_t)gr * W);
            const int b = txi * 8 + g - 2;       // (txi*32+4g-8)/4, aligned
            const float4 P0 = prow[b],     P1 = prow[b + 1], P2 = prow[b + 2],
                         P3 = prow[b + 3], P4 = prow[b + 4];
            const float4 Q0 = qrow[b],     Q1 = qrow[b + 1], Q2 = qrow[b + 2],
                         Q3 = qrow[b + 3], Q4 = qrow[b + 4];
            pv[0] = P0.w;
            pv[1] = P1.x;  pv[2] = P1.y;  pv[3]  = P1.z;  pv[4]  = P1.w;
            pv[5] = P2.x;  pv[6] = P2.y;  pv[7]  = P2.z;  pv[8]  = P2.w;
            pv[9] = P3.x;  pv[10] = P3.y; pv[11] = P3.z;  pv[12] = P3.w;
            pv[13] = P4.x;
            tv[0] = Q0.w;
            tv[1] = Q1.x;  tv[2] = Q1.y;  tv[3]  = Q1.z;  tv[4]  = Q1.w;
            tv[5] = Q2.x;  tv[6] = Q2.y;  tv[7]  = Q2.z;  tv[8]  = Q2.w;
            tv[9] = Q3.x;  tv[10] = Q3.y; tv[11] = Q3.z;  tv[12] = Q3.w;
            tv[13] = Q4.x;
        } else {
            const int cb = col0 + 4 * g;
            const bool rok = (unsigned)gr < (unsigned)H;
            #pragma unroll
            for (int i = 0; i < 14; ++i) {
                const int gc = cb + i;
                const bool ok = rok && ((unsigned)gc < (unsigned)W);
                const size_t idx = (size_t)gr * W + gc;
                pv[i] = ok ? p[idx] : 0.f;
                tv[i] = ok ? q[idx] : 0.f;
            }
        }

        hconv_store(pv, 0, r, g);                 // mu1 source
        hconv_store(tv, 1, r, g);                 // mu2 source

        float prod[14];
        #pragma unroll
        for (int i = 0; i < 14; ++i) prod[i] = pv[i] * tv[i];
        hconv_store(prod, 3, r, g);               // p*t
        #pragma unroll
        for (int i = 0; i < 14; ++i) prod[i] = pv[i] * pv[i];
        hconv_store(prod, 2, r, g);               // p^2
        #pragma unroll
        for (int i = 0; i < 14; ++i) prod[i] = tv[i] * tv[i];
        hconv_store(prod, 4, r, g);               // t^2
    }
    __syncthreads();

    // ---- Vertical pass: unit = (1 col, 8 rows); 32*4 = 128 active threads --
    float local = 0.f;
    if (t < 128) {
        const int c  = t & 31;
        const int rb = (t >> 5) * 8;              // 0,8,16,24

        float a1[8], a2[8], a11[8], a12[8], a22[8];
        auto vconv = [&](int f, float res[8]) {
            float col[18];
            #pragma unroll
            for (int k = 0; k < 18; ++k) col[k] = hb[f][rb + k][c];
            #pragma unroll
            for (int j = 0; j < 8; ++j) {
                float s = 0.f;
                #pragma unroll
                for (int k = 0; k < WSZ; ++k) s += w[k] * col[j + k];
                res[j] = s;
            }
        };
        vconv(0, a1);
        vconv(1, a2);
        vconv(2, a11);
        vconv(3, a12);
        vconv(4, a22);

        const float C1  = 1e-4f;   // (0.01*1)^2
        const float C2  = 9e-4f;   // (0.03*1)^2
        const float EPS = 1e-8f;
        #pragma unroll
        for (int j = 0; j < 8; ++j) {
            const float m1 = a1[j], m2 = a2[j];
            const float m1sq = m1 * m1, m2sq = m2 * m2, m12 = m1 * m2;
            const float v1 = a11[j] - m1sq;
            const float v2 = a22[j] - m2sq;
            const float cv = a12[j] - m12;
            const float num = (2.f * m12 + C1) * (2.f * cv + C2);
            const float den = (m1sq + m2sq + C1) * (v1 + v2 + C2) + EPS;
            local += num / den;
        }
    }

    // Wave shuffle reduce, cross-wave via LDS, one f64 atomic per block.
    #pragma unroll
    for (int off = 32; off > 0; off >>= 1)
        local += __shfl_down(local, off, 64);
    const int lane = t & 63, wid = t >> 6;
    if (lane == 0) wavesum[wid] = local;
    __syncthreads();
    if (t == 0) {
        float s = 0.f;
        #pragma unroll
        for (int wv = 0; wv < NWAVE; ++wv) s += wavesum[wv];
        atomicAdd(acc, (double)s);          // device-scope
        __threadfence();
        const unsigned prev = atomicAdd(counter, 1u);
        if (prev == gridDim.x - 1) {        // last block finalizes
            const double total = atomicAdd(acc, 0.0);
            out[0] = (float)(1.0 - total * invN);
        }
    }
}

extern "C" void kernel_launch(void* const* d_in, const int* in_sizes, int n_in,
                              void* d_out, int out_size, void* d_ws, size_t ws_size,
                              hipStream_t stream)
{
    const float* pred   = (const float*)d_in[0];
    const float* target = (const float*)d_in[1];
    const float* window = (const float*)d_in[2];
    float*  out       = (float*)d_out;
    double* acc       = (double*)d_ws;
    unsigned* counter = (unsigned*)((char*)d_ws + sizeof(double));

    const int B = 16, C = 3, H = 512, W = 512;
    const int n_img = B * C;
    const int tiles = n_img * (H / TILE) * (W / TILE);   // 12288

    // ws is re-poisoned 0xAA before every timed launch: zero acc + counter.
    hipMemsetAsync(d_ws, 0, 16, stream);

    const double invN = 1.0 / ((double)n_img * H * W);
    ssim_fused_kernel<<<tiles, BLOCK, 0, stream>>>(
        pred, target, window, acc, counter, out, H, W, invN);
}

// Round 4
// 571.464 us; speedup vs baseline: 1.3414x; 1.3414x over previous
//
#include <hip/hip_runtime.h>

// SSIM loss, fused separable. B*C=48 images of 512x512 fp32, 11x11 Gaussian
// window, separable via row-sums (w1[i] = sum_j window[i][j]; sum(w1)==1).
//
// Round-4: kill the scratch spill for real. Rounds 2-3 regressed because
// local arrays were passed to lambdas (array->pointer decay defeats SROA ->
// allocas demoted to scratch -> 300-400 MB of HBM scratch traffic,
// WRITE_SIZE counter). Round 4 rule: NO function/lambda ever receives a
// local array; every array lives in one scope and is only indexed with
// unroll-constant indices. h-conv is a macro (textual inline).
//  - h-pass: (1 row x 4 cols)/thread; interior tiles use aligned global
//    float4 loads extracted BY NAME; border tiles guarded scalar loads.
//    hb written with lane-contiguous ds_write_b128 (conflict-free).
//  - v-pass: (1 col x 8 rows)/thread, 128 threads; bank = lane&31 ->
//    2-way aliasing = free on CDNA4.
//  - finalize folded in via last-block-done counter.

#define WSZ   11
#define RAD   5
#define TILE  32
#define IN    42          // TILE + 2*RAD
#define BLOCK 256
#define NWAVE (BLOCK/64)

// Horizontal 11-tap conv of src[0..13] -> 4 outputs -> one b128 store.
// Pure textual expansion: src stays SROA-able (constant indices only).
#define HCONV_STORE(src, f)                                              \
    {                                                                    \
        float s0 = 0.f, s1 = 0.f, s2 = 0.f, s3 = 0.f;                    \
        _Pragma("unroll")                                                \
        for (int k = 0; k < WSZ; ++k) {                                  \
            const float wk = w[k];                                       \
            s0 += wk * src[k];                                           \
            s1 += wk * src[k + 1];                                       \
            s2 += wk * src[k + 2];                                       \
            s3 += wk * src[k + 3];                                       \
        }                                                                \
        *reinterpret_cast<float4*>(&hb[f][r][4 * g]) =                   \
            make_float4(s0, s1, s2, s3);                                 \
    }

__global__ __launch_bounds__(BLOCK) void ssim_fused_kernel(
    const float* __restrict__ pred,
    const float* __restrict__ target,
    const float* __restrict__ window,
    double* __restrict__ acc,
    unsigned* __restrict__ counter,
    float* __restrict__ out,
    int H, int W, double invN)
{
    __shared__ float hb[5][IN][TILE];   // h-blurred: mu1s, mu2s, pp, pt, tt
    __shared__ float w1s[WSZ];
    __shared__ float wavesum[NWAVE];

    const int t = threadIdx.x;

    // Recover separable 1D window (row sums of the 2D window).
    if (t < WSZ) {
        float s = 0.f;
        #pragma unroll
        for (int j = 0; j < WSZ; ++j) s += window[t * WSZ + j];
        w1s[t] = s;
    }

    const int tiles_x = W / TILE;
    const int tiles_per_img = tiles_x * (H / TILE);
    const int img = blockIdx.x / tiles_per_img;
    const int rem = blockIdx.x % tiles_per_img;
    const int tyi = rem / tiles_x;
    const int txi = rem % tiles_x;
    const int row0 = tyi * TILE - RAD;
    const int col0 = txi * TILE - RAD;

    const float* __restrict__ p = pred   + (size_t)img * H * W;
    const float* __restrict__ q = target + (size_t)img * H * W;

    __syncthreads();
    float w[WSZ];
    #pragma unroll
    for (int k = 0; k < WSZ; ++k) w[k] = w1s[k];

    // Interior iff every float4 the vector path touches is in-bounds:
    // cols [txi*32-8, txi*32+39], rows [tyi*32-5, tyi*32+36].
    const bool interior = (txi > 0) && (txi * TILE + 40 <= W) &&
                          (tyi > 0) && (tyi * TILE + 37 <= H);

    // ---- Horizontal pass: unit u = (row r, col-group g of 4); 42*8=336 ----
    for (int u = t; u < IN * 8; u += BLOCK) {
        const int r = u >> 3, g = u & 7;
        const int gr = row0 + r;

        float pv[14], tv[14];   // abs cols col0+4g .. col0+4g+13
        if (interior) {
            const float4* __restrict__ prow =
                reinterpret_cast<const float4*>(p + (size_t)gr * W);
            const float4* __restrict__ qrow =
                reinterpret_cast<const float4*>(q + (size_t)gr * W);
            const int b = txi * 8 + g - 2;       // (txi*32+4g-8)/4, aligned
            const float4 P0 = prow[b],     P1 = prow[b + 1], P2 = prow[b + 2],
                         P3 = prow[b + 3], P4 = prow[b + 4];
            const float4 Q0 = qrow[b],     Q1 = qrow[b + 1], Q2 = qrow[b + 2],
                         Q3 = qrow[b + 3], Q4 = qrow[b + 4];
            pv[0]  = P0.w;
            pv[1]  = P1.x; pv[2]  = P1.y; pv[3]  = P1.z; pv[4]  = P1.w;
            pv[5]  = P2.x; pv[6]  = P2.y; pv[7]  = P2.z; pv[8]  = P2.w;
            pv[9]  = P3.x; pv[10] = P3.y; pv[11] = P3.z; pv[12] = P3.w;
            pv[13] = P4.x;
            tv[0]  = Q0.w;
            tv[1]  = Q1.x; tv[2]  = Q1.y; tv[3]  = Q1.z; tv[4]  = Q1.w;
            tv[5]  = Q2.x; tv[6]  = Q2.y; tv[7]  = Q2.z; tv[8]  = Q2.w;
            tv[9]  = Q3.x; tv[10] = Q3.y; tv[11] = Q3.z; tv[12] = Q3.w;
            tv[13] = Q4.x;
        } else {
            const int cb = col0 + 4 * g;
            const bool rok = (unsigned)gr < (unsigned)H;
            #pragma unroll
            for (int i = 0; i < 14; ++i) {
                const int gc = cb + i;
                const bool ok = rok && ((unsigned)gc < (unsigned)W);
                const size_t idx = (size_t)gr * W + gc;
                pv[i] = ok ? p[idx] : 0.f;
                tv[i] = ok ? q[idx] : 0.f;
            }
        }

        HCONV_STORE(pv, 0)                      // mu1 source
        HCONV_STORE(tv, 1)                      // mu2 source

        float prod[14];
        #pragma unroll
        for (int i = 0; i < 14; ++i) prod[i] = pv[i] * tv[i];
        HCONV_STORE(prod, 3)                    // p*t
        #pragma unroll
        for (int i = 0; i < 14; ++i) prod[i] = pv[i] * pv[i];
        HCONV_STORE(prod, 2)                    // p^2
        #pragma unroll
        for (int i = 0; i < 14; ++i) prod[i] = tv[i] * tv[i];
        HCONV_STORE(prod, 4)                    // t^2
    }
    __syncthreads();

    // ---- Vertical pass: unit = (1 col, 8 rows); 32*4 = 128 active threads --
    float local = 0.f;
    if (t < 128) {
        const int c  = t & 31;
        const int rb = (t >> 5) * 8;            // 0,8,16,24

        float col[18];
        float a1[8], a2[8], a11[8], a12[8], a22[8];

        #pragma unroll
        for (int k = 0; k < 18; ++k) col[k] = hb[0][rb + k][c];
        #pragma unroll
        for (int j = 0; j < 8; ++j) {
            float s = 0.f;
            #pragma unroll
            for (int k = 0; k < WSZ; ++k) s += w[k] * col[j + k];
            a1[j] = s;
        }
        #pragma unroll
        for (int k = 0; k < 18; ++k) col[k] = hb[1][rb + k][c];
        #pragma unroll
        for (int j = 0; j < 8; ++j) {
            float s = 0.f;
            #pragma unroll
            for (int k = 0; k < WSZ; ++k) s += w[k] * col[j + k];
            a2[j] = s;
        }
        #pragma unroll
        for (int k = 0; k < 18; ++k) col[k] = hb[2][rb + k][c];
        #pragma unroll
        for (int j = 0; j < 8; ++j) {
            float s = 0.f;
            #pragma unroll
            for (int k = 0; k < WSZ; ++k) s += w[k] * col[j + k];
            a11[j] = s;
        }
        #pragma unroll
        for (int k = 0; k < 18; ++k) col[k] = hb[3][rb + k][c];
        #pragma unroll
        for (int j = 0; j < 8; ++j) {
            float s = 0.f;
            #pragma unroll
            for (int k = 0; k < WSZ; ++k) s += w[k] * col[j + k];
            a12[j] = s;
        }
        #pragma unroll
        for (int k = 0; k < 18; ++k) col[k] = hb[4][rb + k][c];
        #pragma unroll
        for (int j = 0; j < 8; ++j) {
            float s = 0.f;
            #pragma unroll
            for (int k = 0; k < WSZ; ++k) s += w[k] * col[j + k];
            a22[j] = s;
        }

        const float C1  = 1e-4f;   // (0.01*1)^2
        const float C2  = 9e-4f;   // (0.03*1)^2
        const float EPS = 1e-8f;
        #pragma unroll
        for (int j = 0; j < 8; ++j) {
            const float m1 = a1[j], m2 = a2[j];
            const float m1sq = m1 * m1, m2sq = m2 * m2, m12 = m1 * m2;
            const float v1 = a11[j] - m1sq;
            const float v2 = a22[j] - m2sq;
            const float cv = a12[j] - m12;
            const float num = (2.f * m12 + C1) * (2.f * cv + C2);
            const float den = (m1sq + m2sq + C1) * (v1 + v2 + C2) + EPS;
            local += num / den;
        }
    }

    // Wave shuffle reduce, cross-wave via LDS, one f64 atomic per block.
    #pragma unroll
    for (int off = 32; off > 0; off >>= 1)
        local += __shfl_down(local, off, 64);
    const int lane = t & 63, wid = t >> 6;
    if (lane == 0) wavesum[wid] = local;
    __syncthreads();
    if (t == 0) {
        float s = 0.f;
        #pragma unroll
        for (int wv = 0; wv < NWAVE; ++wv) s += wavesum[wv];
        atomicAdd(acc, (double)s);          // device-scope
        __threadfence();
        const unsigned prev = atomicAdd(counter, 1u);
        if (prev == gridDim.x - 1) {        // last block finalizes
            const double total = atomicAdd(acc, 0.0);
            out[0] = (float)(1.0 - total * invN);
        }
    }
}

extern "C" void kernel_launch(void* const* d_in, const int* in_sizes, int n_in,
                              void* d_out, int out_size, void* d_ws, size_t ws_size,
                              hipStream_t stream)
{
    const float* pred   = (const float*)d_in[0];
    const float* target = (const float*)d_in[1];
    const float* window = (const float*)d_in[2];
    float*  out       = (float*)d_out;
    double* acc       = (double*)d_ws;
    unsigned* counter = (unsigned*)((char*)d_ws + sizeof(double));

    const int B = 16, C = 3, H = 512, W = 512;
    const int n_img = B * C;
    const int tiles = n_img * (H / TILE) * (W / TILE);   // 12288

    // ws is re-poisoned 0xAA before every timed launch: zero acc + counter.
    hipMemsetAsync(d_ws, 0, 16, stream);

    const double invN = 1.0 / ((double)n_img * H * W);
    ssim_fused_kernel<<<tiles, BLOCK, 0, stream>>>(
        pred, target, window, acc, counter, out, H, W, invN);
}

// Round 5
// 231.434 us; speedup vs baseline: 3.3122x; 2.4692x over previous
//
#include <hip/hip_runtime.h>

// SSIM loss, fused separable. B*C=48 images of 512x512 fp32, 11x11 Gaussian
// window, separable via row-sums (w1[i] = sum_j window[i][j]; sum(w1)==1).
//
// Round-5: round-4 compute body (spill-free; WRITE_SIZE 768 KB confirmed)
// with the serializing tail removed. Round 4's folded finalize
// (__threadfence + RETURNING same-address atomicAdd(counter) per block)
// cost ~40 ns x 12288 blocks ~ 460 us of all-pipes-idle serialization.
// Round 5: fire-and-forget f64 atomicAdd spread over 128 slots
// (blockIdx&127), separate 1-block finalize kernel (round-1 style, which
// measured 179 us total with the SAME grid and atomic count).
//  - h-pass: (1 row x 4 cols)/thread; interior tiles use aligned global
//    float4 loads extracted BY NAME (constant indices only -> SROA-safe;
//    NEVER pass a local array to a function/lambda). Border tiles guarded
//    scalar. hb written with lane-contiguous ds_write_b128.
//  - v-pass: (1 col x 8 rows)/thread, 128 threads; bank = lane&31 ->
//    2-way aliasing = free on CDNA4.

#define WSZ   11
#define RAD   5
#define TILE  32
#define IN    42          // TILE + 2*RAD
#define BLOCK 256
#define NWAVE (BLOCK/64)
#define NSLOT 128

// Horizontal 11-tap conv of src[0..13] -> 4 outputs -> one b128 store.
// Pure textual expansion: src stays SROA-able (constant indices only).
#define HCONV_STORE(src, f)                                              \
    {                                                                    \
        float s0 = 0.f, s1 = 0.f, s2 = 0.f, s3 = 0.f;                    \
        _Pragma("unroll")                                                \
        for (int k = 0; k < WSZ; ++k) {                                  \
            const float wk = w[k];                                       \
            s0 += wk * src[k];                                           \
            s1 += wk * src[k + 1];                                       \
            s2 += wk * src[k + 2];                                       \
            s3 += wk * src[k + 3];                                       \
        }                                                                \
        *reinterpret_cast<float4*>(&hb[f][r][4 * g]) =                   \
            make_float4(s0, s1, s2, s3);                                 \
    }

__global__ __launch_bounds__(BLOCK) void ssim_fused_kernel(
    const float* __restrict__ pred,
    const float* __restrict__ target,
    const float* __restrict__ window,
    double* __restrict__ acc,          // NSLOT slots
    int H, int W)
{
    __shared__ float hb[5][IN][TILE];   // h-blurred: mu1s, mu2s, pp, pt, tt
    __shared__ float w1s[WSZ];
    __shared__ float wavesum[NWAVE];

    const int t = threadIdx.x;

    // Recover separable 1D window (row sums of the 2D window).
    if (t < WSZ) {
        float s = 0.f;
        #pragma unroll
        for (int j = 0; j < WSZ; ++j) s += window[t * WSZ + j];
        w1s[t] = s;
    }

    const int tiles_x = W / TILE;
    const int tiles_per_img = tiles_x * (H / TILE);
    const int img = blockIdx.x / tiles_per_img;
    const int rem = blockIdx.x % tiles_per_img;
    const int tyi = rem / tiles_x;
    const int txi = rem % tiles_x;
    const int row0 = tyi * TILE - RAD;
    const int col0 = txi * TILE - RAD;

    const float* __restrict__ p = pred   + (size_t)img * H * W;
    const float* __restrict__ q = target + (size_t)img * H * W;

    __syncthreads();
    float w[WSZ];
    #pragma unroll
    for (int k = 0; k < WSZ; ++k) w[k] = w1s[k];

    // Interior iff every float4 the vector path touches is in-bounds:
    // cols [txi*32-8, txi*32+39], rows [tyi*32-5, tyi*32+36].
    const bool interior = (txi > 0) && (txi * TILE + 40 <= W) &&
                          (tyi > 0) && (tyi * TILE + 37 <= H);

    // ---- Horizontal pass: unit u = (row r, col-group g of 4); 42*8=336 ----
    for (int u = t; u < IN * 8; u += BLOCK) {
        const int r = u >> 3, g = u & 7;
        const int gr = row0 + r;

        float pv[14], tv[14];   // abs cols col0+4g .. col0+4g+13
        if (interior) {
            const float4* __restrict__ prow =
                reinterpret_cast<const float4*>(p + (size_t)gr * W);
            const float4* __restrict__ qrow =
                reinterpret_cast<const float4*>(q + (size_t)gr * W);
            const int b = txi * 8 + g - 2;       // (txi*32+4g-8)/4, aligned
            const float4 P0 = prow[b],     P1 = prow[b + 1], P2 = prow[b + 2],
                         P3 = prow[b + 3], P4 = prow[b + 4];
            const float4 Q0 = qrow[b],     Q1 = qrow[b + 1], Q2 = qrow[b + 2],
                         Q3 = qrow[b + 3], Q4 = qrow[b + 4];
            pv[0]  = P0.w;
            pv[1]  = P1.x; pv[2]  = P1.y; pv[3]  = P1.z; pv[4]  = P1.w;
            pv[5]  = P2.x; pv[6]  = P2.y; pv[7]  = P2.z; pv[8]  = P2.w;
            pv[9]  = P3.x; pv[10] = P3.y; pv[11] = P3.z; pv[12] = P3.w;
            pv[13] = P4.x;
            tv[0]  = Q0.w;
            tv[1]  = Q1.x; tv[2]  = Q1.y; tv[3]  = Q1.z; tv[4]  = Q1.w;
            tv[5]  = Q2.x; tv[6]  = Q2.y; tv[7]  = Q2.z; tv[8]  = Q2.w;
            tv[9]  = Q3.x; tv[10] = Q3.y; tv[11] = Q3.z; tv[12] = Q3.w;
            tv[13] = Q4.x;
        } else {
            const int cb = col0 + 4 * g;
            const bool rok = (unsigned)gr < (unsigned)H;
            #pragma unroll
            for (int i = 0; i < 14; ++i) {
                const int gc = cb + i;
                const bool ok = rok && ((unsigned)gc < (unsigned)W);
                const size_t idx = (size_t)gr * W + gc;
                pv[i] = ok ? p[idx] : 0.f;
                tv[i] = ok ? q[idx] : 0.f;
            }
        }

        HCONV_STORE(pv, 0)                      // mu1 source
        HCONV_STORE(tv, 1)                      // mu2 source

        float prod[14];
        #pragma unroll
        for (int i = 0; i < 14; ++i) prod[i] = pv[i] * tv[i];
        HCONV_STORE(prod, 3)                    // p*t
        #pragma unroll
        for (int i = 0; i < 14; ++i) prod[i] = pv[i] * pv[i];
        HCONV_STORE(prod, 2)                    // p^2
        #pragma unroll
        for (int i = 0; i < 14; ++i) prod[i] = tv[i] * tv[i];
        HCONV_STORE(prod, 4)                    // t^2
    }
    __syncthreads();

    // ---- Vertical pass: unit = (1 col, 8 rows); 32*4 = 128 active threads --
    float local = 0.f;
    if (t < 128) {
        const int c  = t & 31;
        const int rb = (t >> 5) * 8;            // 0,8,16,24

        float col[18];
        float a1[8], a2[8], a11[8], a12[8], a22[8];

        #pragma unroll
        for (int k = 0; k < 18; ++k) col[k] = hb[0][rb + k][c];
        #pragma unroll
        for (int j = 0; j < 8; ++j) {
            float s = 0.f;
            #pragma unroll
            for (int k = 0; k < WSZ; ++k) s += w[k] * col[j + k];
            a1[j] = s;
        }
        #pragma unroll
        for (int k = 0; k < 18; ++k) col[k] = hb[1][rb + k][c];
        #pragma unroll
        for (int j = 0; j < 8; ++j) {
            float s = 0.f;
            #pragma unroll
            for (int k = 0; k < WSZ; ++k) s += w[k] * col[j + k];
            a2[j] = s;
        }
        #pragma unroll
        for (int k = 0; k < 18; ++k) col[k] = hb[2][rb + k][c];
        #pragma unroll
        for (int j = 0; j < 8; ++j) {
            float s = 0.f;
            #pragma unroll
            for (int k = 0; k < WSZ; ++k) s += w[k] * col[j + k];
            a11[j] = s;
        }
        #pragma unroll
        for (int k = 0; k < 18; ++k) col[k] = hb[3][rb + k][c];
        #pragma unroll
        for (int j = 0; j < 8; ++j) {
            float s = 0.f;
            #pragma unroll
            for (int k = 0; k < WSZ; ++k) s += w[k] * col[j + k];
            a12[j] = s;
        }
        #pragma unroll
        for (int k = 0; k < 18; ++k) col[k] = hb[4][rb + k][c];
        #pragma unroll
        for (int j = 0; j < 8; ++j) {
            float s = 0.f;
            #pragma unroll
            for (int k = 0; k < WSZ; ++k) s += w[k] * col[j + k];
            a22[j] = s;
        }

        const float C1  = 1e-4f;   // (0.01*1)^2
        const float C2  = 9e-4f;   // (0.03*1)^2
        const float EPS = 1e-8f;
        #pragma unroll
        for (int j = 0; j < 8; ++j) {
            const float m1 = a1[j], m2 = a2[j];
            const float m1sq = m1 * m1, m2sq = m2 * m2, m12 = m1 * m2;
            const float v1 = a11[j] - m1sq;
            const float v2 = a22[j] - m2sq;
            const float cv = a12[j] - m12;
            const float num = (2.f * m12 + C1) * (2.f * cv + C2);
            const float den = (m1sq + m2sq + C1) * (v1 + v2 + C2) + EPS;
            local += num / den;
        }
    }

    // Wave shuffle reduce, cross-wave via LDS, one fire-and-forget f64
    // atomic per block into one of 128 slots (no same-address contention).
    #pragma unroll
    for (int off = 32; off > 0; off >>= 1)
        local += __shfl_down(local, off, 64);
    const int lane = t & 63, wid = t >> 6;
    if (lane == 0) wavesum[wid] = local;
    __syncthreads();
    if (t == 0) {
        float s = 0.f;
        #pragma unroll
        for (int wv = 0; wv < NWAVE; ++wv) s += wavesum[wv];
        atomicAdd(&acc[blockIdx.x & (NSLOT - 1)], (double)s);
    }
}

__global__ void ssim_finalize_kernel(const double* __restrict__ acc,
                                     float* __restrict__ out, double invN)
{
    // Single wave: lane l sums slots l, l+64.
    const int l = threadIdx.x;
    double s = acc[l] + acc[l + 64];
    #pragma unroll
    for (int off = 32; off > 0; off >>= 1)
        s += __shfl_down(s, off, 64);
    if (l == 0) out[0] = (float)(1.0 - s * invN);
}

extern "C" void kernel_launch(void* const* d_in, const int* in_sizes, int n_in,
                              void* d_out, int out_size, void* d_ws, size_t ws_size,
                              hipStream_t stream)
{
    const float* pred   = (const float*)d_in[0];
    const float* target = (const float*)d_in[1];
    const float* window = (const float*)d_in[2];
    float*  out = (float*)d_out;
    double* acc = (double*)d_ws;

    const int B = 16, C = 3, H = 512, W = 512;
    const int n_img = B * C;
    const int tiles = n_img * (H / TILE) * (W / TILE);   // 12288

    // ws is re-poisoned 0xAA before every timed launch: zero the slots.
    hipMemsetAsync(d_ws, 0, NSLOT * sizeof(double), stream);

    ssim_fused_kernel<<<tiles, BLOCK, 0, stream>>>(
        pred, target, window, acc, H, W);

    const double invN = 1.0 / ((double)n_img * H * W);
    ssim_finalize_kernel<<<1, 64, 0, stream>>>(acc, out, invN);
}